// Round 16
// baseline (182.726 us; speedup 1.0000x reference)
//
#include <hip/hip_runtime.h>

#define NN 768
#define NPAIRS ((NN * (NN - 1)) / 2)   // 294528
#define MARGIN_F 0.01f
#define CHUNK 96                       // k-nodes per thread (768/8)
#define NCHUNK 8

// Pre-pass: pack per-node (x, y, x^2+y^2, 0) into d_ws for scalar dwordx4 loads.
__global__ __launch_bounds__(256) void gg_pre(const float* __restrict__ pos,
                                              float4* __restrict__ nd) {
    int i = blockIdx.x * blockDim.x + threadIdx.x;
    if (i < NN) {
        float x = pos[2 * i], y = pos[2 * i + 1];
        nd[i] = make_float4(x, y, fmaf(x, x, y * y), 0.0f);
    }
}

__global__ __launch_bounds__(256) void gg_main(const float* __restrict__ pos,
                                               const float4* __restrict__ nd,
                                               float* __restrict__ out,
                                               float inv_total) {
    int p = blockIdx.x * blockDim.x + threadIdx.x;
    int kbase = blockIdx.y * CHUNK;
    float acc = 0.0f;

    if (p < NPAIRS) {
        // ---- unrank linear pair index p -> (i, j), i < j ----
        const float A = 2.0f * NN - 1.0f;          // 1535
        float disc = A * A - 8.0f * (float)p;      // integers < 2^24, exact in f32
        int i = (int)((A - __builtin_amdgcn_sqrtf(disc)) * 0.5f);
        if (i < 0) i = 0;
        if (i > NN - 2) i = NN - 2;
        while (((i + 1) * (2 * NN - 1 - (i + 1))) / 2 <= p) ++i;
        while ((i * (2 * NN - 1 - i)) / 2 > p) --i;
        int off = (i * (2 * NN - 1 - i)) / 2;
        int j = i + 1 + (p - off);

        // ---- per-pair: midpoint, radius, quadratic-form constants ----
        float xix = pos[2 * i], xiy = pos[2 * i + 1];
        float xjx = pos[2 * j], xjy = pos[2 * j + 1];
        float mx = 0.5f * (xix + xjx);
        float my = 0.5f * (xiy + xjy);
        float ddx = xix - xjx, ddy = xiy - xjy;
        float r  = 0.5f * __builtin_amdgcn_sqrtf(fmaf(ddx, ddx, ddy * ddy)) + MARGIN_F;
        float cx = -2.0f * mx;
        float cy = -2.0f * my;
        float cc = fmaf(mx, mx, my * my);          // |mid|^2

        // ---- inner loop: dist^2 via quadratic form; sqrt via d2*rsq(d2) ----
        // nd[k] wave-uniform -> s_load_dwordx4. 8 VALU/iter if rsq is fast.
        // d2<=0 (cancellation) -> rsq gives NaN/inf -> fmaxf(r-NaN,0)=0, correct.
        #pragma unroll 8
        for (int k = kbase; k < kbase + CHUNK; ++k) {
            float4 n = nd[k];
            float c  = cc + n.z;
            float d2 = fmaf(n.x, cx, fmaf(n.y, cy, c));
            float d  = d2 * __builtin_amdgcn_rsqf(d2);   // d = sqrt(d2)
            float t  = fmaxf(r - d, 0.0f);
            acc = fmaf(t, t, acc);
        }
    }

    // ---- wave reduce (64 lanes) ----
    for (int o = 32; o > 0; o >>= 1) acc += __shfl_down(acc, o);

    __shared__ float ws[4];
    int lane = threadIdx.x & 63;
    int wid  = threadIdx.x >> 6;
    if (lane == 0) ws[wid] = acc;
    __syncthreads();
    if (threadIdx.x == 0) {
        float s = (ws[0] + ws[1]) + (ws[2] + ws[3]);
        atomicAdd(out, s * inv_total);
    }
}

extern "C" void kernel_launch(void* const* d_in, const int* in_sizes, int n_in,
                              void* d_out, int out_size, void* d_ws, size_t ws_size,
                              hipStream_t stream) {
    const float* pos = (const float*)d_in[0];
    float* out = (float*)d_out;
    float4* nd = (float4*)d_ws;

    // d_out / d_ws re-poisoned 0xAA before every launch
    hipMemsetAsync(out, 0, sizeof(float), stream);
    gg_pre<<<3, 256, 0, stream>>>(pos, nd);

    double total = (double)NN * (double)NPAIRS;
    float inv_total = (float)(1.0 / total);

    dim3 grid((NPAIRS + 255) / 256, NCHUNK);     // 1151 x 8 blocks
    gg_main<<<grid, 256, 0, stream>>>(pos, nd, out, inv_total);
}

// Round 18
// 119.813 us; speedup vs baseline: 1.5251x; 1.5251x over previous
//
#include <hip/hip_runtime.h>

#define NN 768
#define NPAIRS ((NN * (NN - 1)) / 2)   // 294528
#define MARGIN_F 0.01f
#define CHUNK 256                      // k-nodes per thread (768/3) — R6-exact
#define NCHUNK 3

// Pre-pass: pack per-node (x, y, x^2+y^2, 0) into d_ws for scalar dwordx4 loads.
__global__ __launch_bounds__(256) void gg_pre(const float* __restrict__ pos,
                                              float4* __restrict__ nd) {
    int i = blockIdx.x * blockDim.x + threadIdx.x;
    if (i < NN) {
        float x = pos[2 * i], y = pos[2 * i + 1];
        nd[i] = make_float4(x, y, fmaf(x, x, y * y), 0.0f);
    }
}

__global__ __launch_bounds__(256) void gg_main(const float* __restrict__ pos,
                                               const float4* __restrict__ nd,
                                               float* __restrict__ out,
                                               float inv_total) {
    int p = blockIdx.x * blockDim.x + threadIdx.x;
    int kbase = blockIdx.y * CHUNK;
    float acc = 0.0f;

    if (p < NPAIRS) {
        // ---- unrank linear pair index p -> (i, j), i < j ----
        const float A = 2.0f * NN - 1.0f;          // 1535
        float disc = A * A - 8.0f * (float)p;      // integers < 2^24, exact in f32
        int i = (int)((A - __builtin_amdgcn_sqrtf(disc)) * 0.5f);
        if (i < 0) i = 0;
        if (i > NN - 2) i = NN - 2;
        while (((i + 1) * (2 * NN - 1 - (i + 1))) / 2 <= p) ++i;
        while ((i * (2 * NN - 1 - i)) / 2 > p) --i;
        int off = (i * (2 * NN - 1 - i)) / 2;
        int j = i + 1 + (p - off);

        // ---- per-pair: midpoint, radius, quadratic-form constants ----
        float xix = pos[2 * i], xiy = pos[2 * i + 1];
        float xjx = pos[2 * j], xjy = pos[2 * j + 1];
        float mx = 0.5f * (xix + xjx);
        float my = 0.5f * (xiy + xjy);
        float ddx = xix - xjx, ddy = xiy - xjy;
        float r  = 0.5f * __builtin_amdgcn_sqrtf(fmaf(ddx, ddx, ddy * ddy)) + MARGIN_F;
        float cx = -2.0f * mx;
        float cy = -2.0f * my;
        float cc = fmaf(mx, mx, my * my);          // |mid|^2

        // ---- inner loop (R6-exact except sqrt -> d2*rsq(d2)) ----
        // nd[k] wave-uniform -> s_load_dwordx4.
        // d2<=0 (cancellation) -> rsq NaN/inf -> fmaxf(r-NaN,0)=0, correct.
        #pragma unroll 8
        for (int k = kbase; k < kbase + CHUNK; ++k) {
            float4 n = nd[k];
            float c  = cc + n.z;
            float d2 = fmaf(n.x, cx, fmaf(n.y, cy, c));
            float d  = d2 * __builtin_amdgcn_rsqf(d2);   // d = sqrt(d2)  [ONLY change vs R6]
            float t  = fmaxf(r - d, 0.0f);
            acc = fmaf(t, t, acc);
        }
    }

    // ---- wave reduce (64 lanes) ----
    for (int o = 32; o > 0; o >>= 1) acc += __shfl_down(acc, o);

    __shared__ float ws[4];
    int lane = threadIdx.x & 63;
    int wid  = threadIdx.x >> 6;
    if (lane == 0) ws[wid] = acc;
    __syncthreads();
    if (threadIdx.x == 0) {
        float s = (ws[0] + ws[1]) + (ws[2] + ws[3]);
        atomicAdd(out, s * inv_total);
    }
}

extern "C" void kernel_launch(void* const* d_in, const int* in_sizes, int n_in,
                              void* d_out, int out_size, void* d_ws, size_t ws_size,
                              hipStream_t stream) {
    const float* pos = (const float*)d_in[0];
    float* out = (float*)d_out;
    float4* nd = (float4*)d_ws;

    // d_out / d_ws re-poisoned 0xAA before every launch
    hipMemsetAsync(out, 0, sizeof(float), stream);
    gg_pre<<<3, 256, 0, stream>>>(pos, nd);

    double total = (double)NN * (double)NPAIRS;
    float inv_total = (float)(1.0 / total);

    dim3 grid((NPAIRS + 255) / 256, NCHUNK);     // 1151 x 3 blocks — R6-exact
    gg_main<<<grid, 256, 0, stream>>>(pos, nd, out, inv_total);
}